// Round 1
// baseline (164.143 us; speedup 1.0000x reference)
//
#include <hip/hip_runtime.h>

// DSAttention: causal attention, per-batch tau scale + per-key delta bias.
// out[b,l,h,:] = softmax_s( scale*(tau[b]*(q.k) + delta[b,s]), s<=l ) @ V
// Flash-style: block = (b,h, 64 q-rows); 64-key tiles up to diagonal.
// f16 MFMA 16x16x32 for QK^T and PV; fp32 online softmax (exp2 domain);
// P converted C/D-layout -> A-layout via per-wave LDS round-trip (m120).

typedef _Float16 h8 __attribute__((ext_vector_type(8)));
typedef float f32x4 __attribute__((ext_vector_type(4)));

constexpr int Bc = 2, Lc = 2048, Hc = 8, Ec = 64, Sc = 2048;
constexpr int QT = 64, KT = 64;
constexpr int LDK = 72;   // LDS row stride (halfs): 144B = 16B-aligned, +4 banks/row
constexpr float SCALE = 0.125f;                    // 1/sqrt(64)
constexpr float LOG2E = 1.44269504088896340736f;

__global__ __launch_bounds__(256, 2)
void dsattn(const float* __restrict__ Qg, const float* __restrict__ Kg,
            const float* __restrict__ Vg, const float* __restrict__ taug,
            const float* __restrict__ deltag, float* __restrict__ Og) {
  __shared__ __align__(16) _Float16 Ks[KT * LDK];      // [key][e]
  __shared__ __align__(16) _Float16 Vt[Ec * LDK];      // [e][key] (transposed)
  __shared__ __align__(16) _Float16 Pb[4 * 16 * LDK];  // per-wave [q][key]

  const int tid = threadIdx.x;
  const int wave = tid >> 6, lane = tid & 63;
  const int quad = lane >> 4, l16 = lane & 15;

  const int q_tile = (int)gridDim.x - 1 - (int)blockIdx.x;  // biggest work first
  const int q0 = q_tile * QT;
  const int b = (int)blockIdx.y >> 3, h = (int)blockIdx.y & 7;

  const float ct = taug[b] * (SCALE * LOG2E);

  // ---- Q A-fragments (registers for whole block): A[m=lane&15][k=quad*8+j] ----
  const int qm = q0 + (wave << 4) + l16;
  const float* qp = Qg + (((size_t)b * Lc + qm) * Hc + h) * Ec;
  h8 qfrag[2];
#pragma unroll
  for (int kk = 0; kk < 2; ++kk) {
    float4 a0 = ((const float4*)(qp + quad * 8 + kk * 32))[0];
    float4 a1 = ((const float4*)(qp + quad * 8 + kk * 32))[1];
    h8 t;
    t[0]=(_Float16)a0.x; t[1]=(_Float16)a0.y; t[2]=(_Float16)a0.z; t[3]=(_Float16)a0.w;
    t[4]=(_Float16)a1.x; t[5]=(_Float16)a1.y; t[6]=(_Float16)a1.z; t[7]=(_Float16)a1.w;
    qfrag[kk] = t;
  }

  f32x4 Oacc[4];
#pragma unroll
  for (int nt = 0; nt < 4; ++nt) Oacc[nt] = (f32x4){0.f, 0.f, 0.f, 0.f};
  float mrow[4], lrow[4];
#pragma unroll
  for (int r = 0; r < 4; ++r) { mrow[r] = -1e30f; lrow[r] = 0.f; }

  // staging assignments
  const int srow = tid >> 2;                           // K: row 0..63
  const int sec = (tid & 3) << 4;                      // K: e-chunk of 16
  const int vrp = ((tid >> 3) + 4 * (tid & 7)) & 31;   // V: row-pair (swizzled vs e-group)
  const int ve8 = (tid & 7) << 3;                      // V: e-chunk of 8

  _Float16* pb = &Pb[wave * 16 * LDK];

  for (int kt = 0; kt <= q_tile; ++kt) {
    const int kbase = kt * KT;
    __syncthreads();   // previous iteration's LDS reads done
    // ---- stage K tile -> Ks[key][e] (f16) ----
    {
      const float* kp = Kg + (((size_t)b * Sc + kbase + srow) * Hc + h) * Ec + sec;
      float4 c0 = ((const float4*)kp)[0], c1 = ((const float4*)kp)[1];
      float4 c2 = ((const float4*)kp)[2], c3 = ((const float4*)kp)[3];
      h8 w0, w1;
      w0[0]=(_Float16)c0.x; w0[1]=(_Float16)c0.y; w0[2]=(_Float16)c0.z; w0[3]=(_Float16)c0.w;
      w0[4]=(_Float16)c1.x; w0[5]=(_Float16)c1.y; w0[6]=(_Float16)c1.z; w0[7]=(_Float16)c1.w;
      w1[0]=(_Float16)c2.x; w1[1]=(_Float16)c2.y; w1[2]=(_Float16)c2.z; w1[3]=(_Float16)c2.w;
      w1[4]=(_Float16)c3.x; w1[5]=(_Float16)c3.y; w1[6]=(_Float16)c3.z; w1[7]=(_Float16)c3.w;
      *(h8*)&Ks[srow * LDK + sec] = w0;
      *(h8*)&Ks[srow * LDK + sec + 8] = w1;
    }
    // ---- stage V tile transposed -> Vt[e][key], packed pair writes ----
    {
      const float* vp0 = Vg + (((size_t)b * Sc + kbase + 2 * vrp) * Hc + h) * Ec + ve8;
      const float* vp1 = vp0 + Hc * Ec;
      float4 r00 = ((const float4*)vp0)[0], r01 = ((const float4*)vp0)[1];
      float4 r10 = ((const float4*)vp1)[0], r11 = ((const float4*)vp1)[1];
      float e0[8] = {r00.x, r00.y, r00.z, r00.w, r01.x, r01.y, r01.z, r01.w};
      float e1[8] = {r10.x, r10.y, r10.z, r10.w, r11.x, r11.y, r11.z, r11.w};
#pragma unroll
      for (int j = 0; j < 8; ++j) {
        _Float16 lo = (_Float16)e0[j], hi = (_Float16)e1[j];
        unsigned pk = (unsigned)__builtin_bit_cast(unsigned short, lo)
                    | ((unsigned)__builtin_bit_cast(unsigned short, hi) << 16);
        *(unsigned*)&Vt[(ve8 + j) * LDK + 2 * vrp] = pk;
      }
    }
    __syncthreads();

    // ---- S = Q.K^T : D rows = q (quad*4+r), cols = key (nt*16+l16) ----
    f32x4 Sacc[4];
#pragma unroll
    for (int nt = 0; nt < 4; ++nt) Sacc[nt] = (f32x4){0.f, 0.f, 0.f, 0.f};
#pragma unroll
    for (int kk = 0; kk < 2; ++kk) {
#pragma unroll
      for (int nt = 0; nt < 4; ++nt) {
        h8 bf = *(const h8*)&Ks[(nt * 16 + l16) * LDK + quad * 8 + kk * 32];
        Sacc[nt] = __builtin_amdgcn_mfma_f32_16x16x32_f16(qfrag[kk], bf, Sacc[nt], 0, 0, 0);
      }
    }

    // ---- online softmax (exp2 domain) ----
    float dterm[4];
#pragma unroll
    for (int nt = 0; nt < 4; ++nt)
      dterm[nt] = deltag[(size_t)b * Sc + kbase + nt * 16 + l16] * (SCALE * LOG2E);

    const int qr0 = q0 + (wave << 4) + (quad << 2);
    const bool diag = (kt == q_tile);   // mask only needed on diagonal tile
    float sv[4][4];
#pragma unroll
    for (int nt = 0; nt < 4; ++nt) {
      const int key = kbase + nt * 16 + l16;
#pragma unroll
      for (int r = 0; r < 4; ++r) {
        float s = Sacc[nt][r] * ct + dterm[nt];
        sv[nt][r] = (!diag || key <= qr0 + r) ? s : -1e30f;
      }
    }
    float tmax[4];
#pragma unroll
    for (int r = 0; r < 4; ++r)
      tmax[r] = fmaxf(fmaxf(sv[0][r], sv[1][r]), fmaxf(sv[2][r], sv[3][r]));
#pragma unroll
    for (int off = 1; off < 16; off <<= 1)
#pragma unroll
      for (int r = 0; r < 4; ++r)
        tmax[r] = fmaxf(tmax[r], __shfl_xor(tmax[r], off, 64));

    float alpha[4], rsum[4];
#pragma unroll
    for (int r = 0; r < 4; ++r) {
      float mn = fmaxf(mrow[r], tmax[r]);
      alpha[r] = __builtin_amdgcn_exp2f(mrow[r] - mn);
      mrow[r] = mn;
      rsum[r] = 0.f;
    }
#pragma unroll
    for (int nt = 0; nt < 4; ++nt)
#pragma unroll
      for (int r = 0; r < 4; ++r) {
        float p = __builtin_amdgcn_exp2f(sv[nt][r] - mrow[r]);
        sv[nt][r] = p;
        rsum[r] += p;
      }
#pragma unroll
    for (int off = 1; off < 16; off <<= 1)
#pragma unroll
      for (int r = 0; r < 4; ++r) rsum[r] += __shfl_xor(rsum[r], off, 64);
#pragma unroll
    for (int r = 0; r < 4; ++r) lrow[r] = lrow[r] * alpha[r] + rsum[r];
#pragma unroll
    for (int nt = 0; nt < 4; ++nt)
#pragma unroll
      for (int r = 0; r < 4; ++r) Oacc[nt][r] *= alpha[r];

    // ---- P -> per-wave LDS (becomes A-operand for PV) ----
#pragma unroll
    for (int nt = 0; nt < 4; ++nt)
#pragma unroll
      for (int r = 0; r < 4; ++r)
        pb[((quad << 2) + r) * LDK + nt * 16 + l16] = (_Float16)sv[nt][r];
    asm volatile("s_waitcnt lgkmcnt(0)" ::: "memory");  // intra-wave cross-lane RAW

    // ---- O += P.V ----
#pragma unroll
    for (int kk = 0; kk < 2; ++kk) {
      h8 af = *(const h8*)&pb[l16 * LDK + quad * 8 + kk * 32];
#pragma unroll
      for (int nt = 0; nt < 4; ++nt) {
        h8 vf = *(const h8*)&Vt[(nt * 16 + l16) * LDK + quad * 8 + kk * 32];
        Oacc[nt] = __builtin_amdgcn_mfma_f32_16x16x32_f16(af, vf, Oacc[nt], 0, 0, 0);
      }
    }
  }

  // ---- epilogue: normalize, store fp32 ----
#pragma unroll
  for (int r = 0; r < 4; ++r) {
    const int qrow = q0 + (wave << 4) + (quad << 2) + r;
    const float inv = 1.0f / lrow[r];
    float* op = Og + (((size_t)b * Lc + qrow) * Hc + h) * Ec;
#pragma unroll
    for (int nt = 0; nt < 4; ++nt) op[nt * 16 + l16] = Oacc[nt][r] * inv;
  }
}

extern "C" void kernel_launch(void* const* d_in, const int* in_sizes, int n_in,
                              void* d_out, int out_size, void* d_ws, size_t ws_size,
                              hipStream_t stream) {
  const float* Q = (const float*)d_in[0];
  const float* K = (const float*)d_in[1];
  const float* V = (const float*)d_in[2];
  const float* tau = (const float*)d_in[3];
  const float* delta = (const float*)d_in[4];
  float* O = (float*)d_out;
  dim3 grid(Lc / QT, Bc * Hc);   // 32 q-tiles x 16 (b,h)
  dsattn<<<grid, 256, 0, stream>>>(Q, K, V, tau, delta, O);
}

// Round 3
// 126.714 us; speedup vs baseline: 1.2954x; 1.2954x over previous
//
#include <hip/hip_runtime.h>

// DSAttention flash kernel, round 2 (r2 compile fix: bit_cast cvt_pkrtz result).
// vs r1: rowsum via MFMA ones-trick (no sum shuffles), max reduce via
// DPP (VALU) instead of ds_swizzle, packed P/V LDS writes (write2-shaped),
// double-buffered K/V staging with register prefetch (1 barrier/iter).

typedef _Float16 h8 __attribute__((ext_vector_type(8)));
typedef _Float16 h2 __attribute__((ext_vector_type(2)));
typedef float f32x4 __attribute__((ext_vector_type(4)));

constexpr int Bc = 2, Lc = 2048, Hc = 8, Ec = 64, Sc = 2048;
constexpr int QT = 64, KT = 64;
constexpr int LDK = 72;   // LDS row stride (halfs): 144B, 16B-aligned, +4 banks/row
constexpr float SCALE = 0.125f;
constexpr float LOG2E = 1.44269504088896340736f;

__device__ __forceinline__ h2 pk2(float x, float y) {
  return __builtin_bit_cast(h2, __builtin_amdgcn_cvt_pkrtz(x, y));
}

template <int CTRL>
__device__ __forceinline__ float dpp_f(float x) {
  int r = __builtin_amdgcn_update_dpp(0, __builtin_bit_cast(int, x), CTRL, 0xF, 0xF, true);
  return __builtin_bit_cast(float, r);
}
// max over the 16 lanes of a DPP row: xor1, xor2 (quad_perm), then row_ror 4, 8
__device__ __forceinline__ float rowmax16(float x) {
  x = fmaxf(x, dpp_f<0xB1>(x));    // quad_perm [1,0,3,2]  = xor 1
  x = fmaxf(x, dpp_f<0x4E>(x));    // quad_perm [2,3,0,1]  = xor 2
  x = fmaxf(x, dpp_f<0x124>(x));   // row_ror:4
  x = fmaxf(x, dpp_f<0x128>(x));   // row_ror:8
  return x;
}

__global__ __launch_bounds__(256, 2)
void dsattn(const float* __restrict__ Qg, const float* __restrict__ Kg,
            const float* __restrict__ Vg, const float* __restrict__ taug,
            const float* __restrict__ deltag, float* __restrict__ Og) {
  __shared__ __align__(16) _Float16 Ks[2][KT * LDK];      // [key][e]
  __shared__ __align__(16) _Float16 Vt[2][Ec * LDK];      // [e][key] transposed
  __shared__ __align__(16) _Float16 Pb[4][16 * LDK];      // per-wave [q][key]

  const int tid = threadIdx.x;
  const int wave = tid >> 6, lane = tid & 63;
  const int quad = lane >> 4, l16 = lane & 15;

  const int q_tile = (int)gridDim.x - 1 - (int)blockIdx.x;  // biggest first
  const int q0 = q_tile * QT;
  const int b = (int)blockIdx.y >> 3, h = (int)blockIdx.y & 7;

  const float ct = taug[b] * (SCALE * LOG2E);

  // ---- Q A-fragments: A[m=l16][k=quad*8+j+kk*32] ----
  const int qm = q0 + (wave << 4) + l16;
  const float* qp = Qg + (((size_t)b * Lc + qm) * Hc + h) * Ec;
  h8 qfrag[2];
#pragma unroll
  for (int kk = 0; kk < 2; ++kk) {
    float4 a0 = ((const float4*)(qp + quad * 8 + kk * 32))[0];
    float4 a1 = ((const float4*)(qp + quad * 8 + kk * 32))[1];
    union { h8 v; h2 p[4]; } u;
    u.p[0] = pk2(a0.x, a0.y); u.p[1] = pk2(a0.z, a0.w);
    u.p[2] = pk2(a1.x, a1.y); u.p[3] = pk2(a1.z, a1.w);
    qfrag[kk] = u.v;
  }

  h8 onesf;
#pragma unroll
  for (int j = 0; j < 8; ++j) onesf[j] = (_Float16)1.0f;

  f32x4 Oacc[4], Osum;
#pragma unroll
  for (int nt = 0; nt < 4; ++nt) Oacc[nt] = (f32x4){0.f, 0.f, 0.f, 0.f};
  Osum = (f32x4){0.f, 0.f, 0.f, 0.f};
  float mrow[4];
#pragma unroll
  for (int r = 0; r < 4; ++r) mrow[r] = -1e30f;

  // staging assignments
  const int srow = tid >> 2;                          // K: row 0..63
  const int sec = (tid & 3) << 4;                     // K: e-chunk of 16
  const int vrp = ((tid >> 3) + 4 * (tid & 7)) & 31;  // V: row-pair (swizzled)
  const int ve8 = (tid & 7) << 3;                     // V: e-chunk of 8

  _Float16* pb = &Pb[wave][0];

  float dcur[4];

  // ---- prologue: stage tile 0 into buffer 0 ----
  {
    const float* kp = Kg + (((size_t)b * Sc + srow) * Hc + h) * Ec + sec;
    float4 c0 = ((const float4*)kp)[0], c1 = ((const float4*)kp)[1];
    float4 c2 = ((const float4*)kp)[2], c3 = ((const float4*)kp)[3];
    const float* vp0 = Vg + (((size_t)b * Sc + 2 * vrp) * Hc + h) * Ec + ve8;
    const float* vp1 = vp0 + Hc * Ec;
    float4 r00 = ((const float4*)vp0)[0], r01 = ((const float4*)vp0)[1];
    float4 r10 = ((const float4*)vp1)[0], r11 = ((const float4*)vp1)[1];
#pragma unroll
    for (int nt = 0; nt < 4; ++nt)
      dcur[nt] = deltag[(size_t)b * Sc + nt * 16 + l16] * (SCALE * LOG2E);
    union { h8 v; h2 p[4]; } w0, w1;
    w0.p[0] = pk2(c0.x, c0.y); w0.p[1] = pk2(c0.z, c0.w);
    w0.p[2] = pk2(c1.x, c1.y); w0.p[3] = pk2(c1.z, c1.w);
    w1.p[0] = pk2(c2.x, c2.y); w1.p[1] = pk2(c2.z, c2.w);
    w1.p[2] = pk2(c3.x, c3.y); w1.p[3] = pk2(c3.z, c3.w);
    *(h8*)&Ks[0][srow * LDK + sec] = w0.v;
    *(h8*)&Ks[0][srow * LDK + sec + 8] = w1.v;
    const float e0[8] = {r00.x, r00.y, r00.z, r00.w, r01.x, r01.y, r01.z, r01.w};
    const float e1[8] = {r10.x, r10.y, r10.z, r10.w, r11.x, r11.y, r11.z, r11.w};
#pragma unroll
    for (int j = 0; j < 8; ++j)
      *(h2*)&Vt[0][(ve8 + j) * LDK + 2 * vrp] = pk2(e0[j], e1[j]);
  }

  for (int kt = 0; kt <= q_tile; ++kt) {
    const int cur = kt & 1;
    const bool pf = (kt < q_tile);

    // ---- issue global prefetch for tile kt+1 (regs only) ----
    float4 kn0, kn1, kn2, kn3, vn00, vn01, vn10, vn11;
    float dn[4];
    if (pf) {
      const int nb = (kt + 1) * KT;
      const float* kp = Kg + (((size_t)b * Sc + nb + srow) * Hc + h) * Ec + sec;
      kn0 = ((const float4*)kp)[0]; kn1 = ((const float4*)kp)[1];
      kn2 = ((const float4*)kp)[2]; kn3 = ((const float4*)kp)[3];
      const float* vp0 = Vg + (((size_t)b * Sc + nb + 2 * vrp) * Hc + h) * Ec + ve8;
      const float* vp1 = vp0 + Hc * Ec;
      vn00 = ((const float4*)vp0)[0]; vn01 = ((const float4*)vp0)[1];
      vn10 = ((const float4*)vp1)[0]; vn11 = ((const float4*)vp1)[1];
#pragma unroll
      for (int nt = 0; nt < 4; ++nt)
        dn[nt] = deltag[(size_t)b * Sc + nb + nt * 16 + l16];
    }

    __syncthreads();   // tile kt's LDS writes visible; prev buffer free for reuse

    // ---- S = Q.K^T ----
    f32x4 Sacc[4];
#pragma unroll
    for (int nt = 0; nt < 4; ++nt) Sacc[nt] = (f32x4){0.f, 0.f, 0.f, 0.f};
#pragma unroll
    for (int kk = 0; kk < 2; ++kk) {
#pragma unroll
      for (int nt = 0; nt < 4; ++nt) {
        h8 bf = *(const h8*)&Ks[cur][(nt * 16 + l16) * LDK + quad * 8 + kk * 32];
        Sacc[nt] = __builtin_amdgcn_mfma_f32_16x16x32_f16(qfrag[kk], bf, Sacc[nt], 0, 0, 0);
      }
    }

    // ---- scale + bias + causal mask ----
    const int kbase = kt * KT;
    const int qr0 = q0 + (wave << 4) + (quad << 2);
    const bool diag = (kt == q_tile);
    float sv[4][4];
#pragma unroll
    for (int nt = 0; nt < 4; ++nt) {
      const int key = kbase + nt * 16 + l16;
#pragma unroll
      for (int r = 0; r < 4; ++r) {
        float s = Sacc[nt][r] * ct + dcur[nt];
        sv[nt][r] = (!diag || key <= qr0 + r) ? s : -1e30f;
      }
    }

    // ---- online max (DPP, all-VALU) ----
    float alpha[4];
#pragma unroll
    for (int r = 0; r < 4; ++r) {
      float t = fmaxf(fmaxf(sv[0][r], sv[1][r]), fmaxf(sv[2][r], sv[3][r]));
      t = rowmax16(t);
      float mn = fmaxf(mrow[r], t);
      alpha[r] = __builtin_amdgcn_exp2f(mrow[r] - mn);
      mrow[r] = mn;
    }
#pragma unroll
    for (int nt = 0; nt < 4; ++nt)
#pragma unroll
      for (int r = 0; r < 4; ++r)
        sv[nt][r] = __builtin_amdgcn_exp2f(sv[nt][r] - mrow[r]);

    // rescale accumulators (incl. row-sum tile)
#pragma unroll
    for (int nt = 0; nt < 4; ++nt)
#pragma unroll
      for (int r = 0; r < 4; ++r) Oacc[nt][r] *= alpha[r];
#pragma unroll
    for (int r = 0; r < 4; ++r) Osum[r] *= alpha[r];

    // ---- P -> per-wave LDS, packed via DPP xor1 pairing ----
    {
      const int lo = l16 & 1;
      const int base = (lo ? 32 : 0) + (l16 & ~1);
#pragma unroll
      for (int r = 0; r < 4; ++r) {
        float o0 = dpp_f<0xB1>(sv[0][r]);
        float o1 = dpp_f<0xB1>(sv[1][r]);
        float o2 = dpp_f<0xB1>(sv[2][r]);
        float o3 = dpp_f<0xB1>(sv[3][r]);
        h2 d0 = pk2(lo ? o2 : sv[0][r], lo ? sv[2][r] : o0);
        h2 d1 = pk2(lo ? o3 : sv[1][r], lo ? sv[3][r] : o1);
        _Float16* pp = &pb[((quad << 2) + r) * LDK + base];
        *(h2*)pp = d0;
        *(h2*)(pp + 16) = d1;
      }
    }
    asm volatile("s_waitcnt lgkmcnt(0)" ::: "memory");  // intra-wave RAW on Pb

    // ---- O += P.V ; Osum += P.1 ----
#pragma unroll
    for (int kk = 0; kk < 2; ++kk) {
      h8 af = *(const h8*)&pb[l16 * LDK + quad * 8 + kk * 32];
#pragma unroll
      for (int nt = 0; nt < 4; ++nt) {
        h8 vf = *(const h8*)&Vt[cur][(nt * 16 + l16) * LDK + quad * 8 + kk * 32];
        Oacc[nt] = __builtin_amdgcn_mfma_f32_16x16x32_f16(af, vf, Oacc[nt], 0, 0, 0);
      }
      Osum = __builtin_amdgcn_mfma_f32_16x16x32_f16(af, onesf, Osum, 0, 0, 0);
    }

    // ---- write prefetched tile kt+1 into the other buffer ----
    if (pf) {
      _Float16* ksn = &Ks[cur ^ 1][0];
      _Float16* vtn = &Vt[cur ^ 1][0];
      union { h8 v; h2 p[4]; } w0, w1;
      w0.p[0] = pk2(kn0.x, kn0.y); w0.p[1] = pk2(kn0.z, kn0.w);
      w0.p[2] = pk2(kn1.x, kn1.y); w0.p[3] = pk2(kn1.z, kn1.w);
      w1.p[0] = pk2(kn2.x, kn2.y); w1.p[1] = pk2(kn2.z, kn2.w);
      w1.p[2] = pk2(kn3.x, kn3.y); w1.p[3] = pk2(kn3.z, kn3.w);
      *(h8*)&ksn[srow * LDK + sec] = w0.v;
      *(h8*)&ksn[srow * LDK + sec + 8] = w1.v;
      const float e0[8] = {vn00.x, vn00.y, vn00.z, vn00.w, vn01.x, vn01.y, vn01.z, vn01.w};
      const float e1[8] = {vn10.x, vn10.y, vn10.z, vn10.w, vn11.x, vn11.y, vn11.z, vn11.w};
#pragma unroll
      for (int j = 0; j < 8; ++j)
        *(h2*)&vtn[(ve8 + j) * LDK + 2 * vrp] = pk2(e0[j], e1[j]);
#pragma unroll
      for (int nt = 0; nt < 4; ++nt) dcur[nt] = dn[nt] * (SCALE * LOG2E);
    }
  }

  // ---- epilogue: normalize by MFMA-computed row sums, store fp32 ----
#pragma unroll
  for (int r = 0; r < 4; ++r) {
    const int qrow = q0 + (wave << 4) + (quad << 2) + r;
    const float inv = 1.0f / Osum[r];
    float* op = Og + (((size_t)b * Lc + qrow) * Hc + h) * Ec;
#pragma unroll
    for (int nt = 0; nt < 4; ++nt) op[nt * 16 + l16] = Oacc[nt][r] * inv;
  }
}

extern "C" void kernel_launch(void* const* d_in, const int* in_sizes, int n_in,
                              void* d_out, int out_size, void* d_ws, size_t ws_size,
                              hipStream_t stream) {
  const float* Q = (const float*)d_in[0];
  const float* K = (const float*)d_in[1];
  const float* V = (const float*)d_in[2];
  const float* tau = (const float*)d_in[3];
  const float* delta = (const float*)d_in[4];
  float* O = (float*)d_out;
  dim3 grid(Lc / QT, Bc * Hc);   // 32 q-tiles x 16 (b,h)
  dsattn<<<grid, 256, 0, stream>>>(Q, K, V, tau, delta, O);
}